// Round 9
// baseline (684.761 us; speedup 1.0000x reference)
//
#include <hip/hip_runtime.h>

// Inputs and output are FP32 (per the reference). Internal GEMM/attention
// compute is bf16 MFMA with fp32 accumulate; bf16 stored as unsigned short.

typedef __attribute__((ext_vector_type(8))) short short8;    // 8 bf16 = 1 MFMA A/B frag
typedef __attribute__((ext_vector_type(4))) short short4v;   // 4 bf16 = 8B vector
typedef __attribute__((ext_vector_type(4))) float floatx4;   // MFMA C/D frag
typedef __attribute__((ext_vector_type(4))) int int4v;

__device__ __forceinline__ float bf2f(unsigned short u) {
    return __uint_as_float(((unsigned int)u) << 16);
}
__device__ __forceinline__ unsigned short f2bf(float f) {
    unsigned int u = __float_as_uint(f);
    u += 0x7FFFu + ((u >> 16) & 1u);   // RNE
    return (unsigned short)(u >> 16);
}
__device__ __forceinline__ int pack2bf(float a, float b) {
    return (int)f2bf(a) | ((int)f2bf(b) << 16);
}

// Async global->LDS, 16 B per lane. LDS dest = wave-uniform base + lane*16.
__device__ __forceinline__ void async16(const unsigned short* g, unsigned short* l) {
    __builtin_amdgcn_global_load_lds(
        (const __attribute__((address_space(1))) unsigned int*)g,
        (__attribute__((address_space(3))) unsigned int*)l, 16, 0, 0);
}

// ---------------------------------------------------------------------------
// FP32 -> BF16 elementwise convert. grid = n/1024, block 256.
// ---------------------------------------------------------------------------
__global__ __launch_bounds__(256)
void cvt_f2b(const float* __restrict__ in, unsigned short* __restrict__ out) {
    const int i = (blockIdx.x * 256 + threadIdx.x) * 4;
    float4 v = *(const float4*)&in[i];
    short4v o;
    o[0] = (short)f2bf(v.x); o[1] = (short)f2bf(v.y);
    o[2] = (short)f2bf(v.z); o[3] = (short)f2bf(v.w);
    *(short4v*)&out[i] = o;
}

// ---------------------------------------------------------------------------
// C[M,N] = A[M,K] @ W[N,K]^T (+bias fp32) (+PReLU) (+0.125 scale on cols<qcols)
// bf16 in/out, fp32 acc. 128x128 tile, BK=64, 4 waves in 2x2. m97 staging.
// XCD swizzle: x = M-tile so linear id % 8 = m%8 -> A fetched once per XCD.
// ---------------------------------------------------------------------------
__global__ __launch_bounds__(256)
void gemm_bt(const unsigned short* __restrict__ A,
             const unsigned short* __restrict__ W,
             const float* __restrict__ bias,   // nullable, len N, fp32
             const float* __restrict__ prelu,  // nullable, scalar, fp32
             unsigned short* __restrict__ C,
             int N, int K, int qcols) {
    __shared__ alignas(16) unsigned short lA[128 * 64];
    __shared__ alignas(16) unsigned short lB[128 * 64];

    const int m0 = blockIdx.x * 128;   // x = M-tile (XCD locality for A)
    const int n0 = blockIdx.y * 128;
    const int tid  = threadIdx.x;
    const int lane = tid & 63;
    const int wave = tid >> 6;
    const int wm = (wave >> 1) * 64;
    const int wn = (wave & 1) * 64;
    const int lr = lane & 15;
    const int lq = lane >> 4;

    floatx4 acc[4][4] = {};

    for (int k0 = 0; k0 < K; k0 += 64) {
        #pragma unroll
        for (int it = 0; it < 4; ++it) {
            const int i = it * 256 + tid;
            const int row = i >> 3;
            const int col = (i & 7) << 3;
            unsigned short* dstA = &lA[(it * 256 + wave * 64) * 8];
            unsigned short* dstB = &lB[(it * 256 + wave * 64) * 8];
            async16(&A[(size_t)(m0 + row) * K + k0 + col], dstA);
            async16(&W[(size_t)(n0 + row) * K + k0 + col], dstB);
        }
        __syncthreads();
        #pragma unroll
        for (int s = 0; s < 2; ++s) {
            short8 af[4], bfr[4];
            #pragma unroll
            for (int i = 0; i < 4; ++i)
                af[i] = *(const short8*)&lA[(wm + i * 16 + lr) * 64 + s * 32 + lq * 8];
            #pragma unroll
            for (int j = 0; j < 4; ++j)
                bfr[j] = *(const short8*)&lB[(wn + j * 16 + lr) * 64 + s * 32 + lq * 8];
            #pragma unroll
            for (int i = 0; i < 4; ++i)
                #pragma unroll
                for (int j = 0; j < 4; ++j)
                    acc[i][j] = __builtin_amdgcn_mfma_f32_16x16x32_bf16(
                        af[i], bfr[j], acc[i][j], 0, 0, 0);
        }
        __syncthreads();
    }

    const bool has_prelu = (prelu != nullptr);
    const float slope = has_prelu ? prelu[0] : 0.f;
    #pragma unroll
    for (int j = 0; j < 4; ++j) {
        int gc = n0 + wn + j * 16 + lr;
        float bv = bias ? bias[gc] : 0.f;
        const float cscale = (gc < qcols) ? 0.125f : 1.f;
        #pragma unroll
        for (int i = 0; i < 4; ++i) {
            int gr = m0 + wm + i * 16 + lq * 4;
            #pragma unroll
            for (int r = 0; r < 4; ++r) {
                float v = acc[i][j][r] + bv;
                if (has_prelu && v < 0.f) v *= slope;
                C[(size_t)(gr + r) * N + gc] = f2bf(v * cscale);
            }
        }
    }
}

// ---------------------------------------------------------------------------
// V transpose: vt[(bh*64 + d)*2048 + key] = qkv[(b*2048+key)*3072 + 2048 + h*64 + d]
// ---------------------------------------------------------------------------
__global__ __launch_bounds__(256)
void transpose_v(const unsigned short* __restrict__ qkv,
                 unsigned short* __restrict__ vt) {
    const int kt = blockIdx.x;   // key tile 0..31
    const int bh = blockIdx.y;   // 0..63
    const int b = bh >> 4, h = bh & 15;
    __shared__ unsigned short tile[64 * 65];
    for (int t = threadIdx.x; t < 512; t += 256) {
        const int key = t >> 3, c8 = (t & 7) << 3;
        short8 v8 = *(const short8*)&qkv[((size_t)(b * 2048 + kt * 64 + key)) * 3072 +
                                         2048 + h * 64 + c8];
        #pragma unroll
        for (int e = 0; e < 8; ++e)
            tile[key * 65 + c8 + e] = (unsigned short)v8[e];
    }
    __syncthreads();
    for (int t = threadIdx.x; t < 512; t += 256) {
        const int d = t >> 3, k8 = (t & 7) << 3;
        short8 o;
        #pragma unroll
        for (int e = 0; e < 8; ++e)
            o[e] = (short)tile[(k8 + e) * 65 + d];
        *(short8*)&vt[((size_t)bh * 64 + d) * 2048 + kt * 64 + k8] = o;
    }
}

// ---------------------------------------------------------------------------
// Flash attention, S^T formulation, NO-MAX softmax, SPLIT-K x2 + double-buffer.
// Grid 1024: id = half*512 + qtb*64 + bh (id%8 = bh%8 -> both halves of a
// (b,h) share an XCD). Each block: keys [half*1024, half*1024+1024), 16 chunks,
// ping-pong K/V LDS staging via async16 (prefetch chunk c+1 during compute c).
// Partials: O (bf16, unnormalized) and l (fp32) -> combined by attn_combine.
// ---------------------------------------------------------------------------
__global__ __launch_bounds__(256)
void attn_kernel(const unsigned short* __restrict__ qkv,
                 const unsigned short* __restrict__ vt,
                 unsigned short* __restrict__ opart,   // [2][8192][1024] bf16
                 float* __restrict__ lpart) {          // [2][8192][16] fp32
    const int id  = blockIdx.x;
    const int half = id >> 9;          // 0..1
    const int rem  = id & 511;
    const int qtb  = rem >> 6;         // 0..7
    const int bh   = rem & 63;         // 0..63
    const int b = bh >> 4, h = bh & 15;
    const int tid = threadIdx.x;
    const int lane = tid & 63;
    const int wave = tid >> 6;
    const int lr = lane & 15;
    const int lq = lane >> 4;
    const int q0 = (qtb * 4 + wave) * 64;
    const int kbase = half * 1024;
    const size_t row0 = (size_t)(b * 2048) * 3072;

    __shared__ alignas(16) unsigned short lK[2][64 * 64];   // [key][d]
    __shared__ alignas(16) unsigned short lV[2][64 * 64];   // [d][key]

    // Q fragments (B-operand): [n = q = j*16+lr][k = s*32 + lq*8 + jj]
    short8 qf[4][2];
    #pragma unroll
    for (int j = 0; j < 4; ++j)
        #pragma unroll
        for (int s = 0; s < 2; ++s)
            qf[j][s] = *(const short8*)&qkv[row0 + (size_t)(q0 + j * 16 + lr) * 3072 +
                                            h * 64 + s * 32 + lq * 8];

    floatx4 oacc[4][4] = {};   // [dtile i][qtile j]: d=i*16+lq*4+r, q=j*16+lr
    float l_i[4] = {0.f, 0.f, 0.f, 0.f};

    const int src0 = lr + ((lq & 1) * 2) * 16;
    const int src1 = src0 + 16;
    const bool hi = (lq >> 1) != 0;

    // Stage chunk into buffer bi.
    auto stage = [&](int bi, int kc) {
        #pragma unroll
        for (int it = 0; it < 2; ++it) {
            const int i = it * 256 + tid;
            const int row = i >> 3;
            const int col = (i & 7) << 3;
            async16(&qkv[row0 + (size_t)(kc + row) * 3072 + 1024 + h * 64 + col],
                    &lK[bi][(it * 256 + wave * 64) * 8]);
            async16(&vt[((size_t)bh * 64 + row) * 2048 + kc + col],
                    &lV[bi][(it * 256 + wave * 64) * 8]);
        }
    };

    stage(0, kbase);
    __syncthreads();

    for (int c = 0; c < 16; ++c) {
        const int cur = c & 1;
        if (c + 1 < 16) stage(cur ^ 1, kbase + (c + 1) * 64);

        // S^T = K·Q^T
        floatx4 sacc[4][4] = {};   // [keytile i][qtile j]: key=i*16+lq*4+r
        #pragma unroll
        for (int s = 0; s < 2; ++s) {
            short8 kf[4];
            #pragma unroll
            for (int i = 0; i < 4; ++i)
                kf[i] = *(const short8*)&lK[cur][(i * 16 + lr) * 64 + s * 32 + lq * 8];
            #pragma unroll
            for (int i = 0; i < 4; ++i)
                #pragma unroll
                for (int j = 0; j < 4; ++j)
                    sacc[i][j] = __builtin_amdgcn_mfma_f32_16x16x32_bf16(
                        kf[i], qf[j][s], sacc[i][j], 0, 0, 0);
        }

        // P = exp(S), packed to bf16 pairs; l accumulated per-lane.
        int pkd[4][4][2];
        #pragma unroll
        for (int i = 0; i < 4; ++i)
            #pragma unroll
            for (int j = 0; j < 4; ++j) {
                const float e0 = __expf(sacc[i][j][0]);
                const float e1 = __expf(sacc[i][j][1]);
                const float e2 = __expf(sacc[i][j][2]);
                const float e3 = __expf(sacc[i][j][3]);
                l_i[j] += (e0 + e1) + (e2 + e3);
                pkd[i][j][0] = pack2bf(e0, e1);
                pkd[i][j][1] = pack2bf(e2, e3);
            }

        // O^T += V^T·P^T  (A = V^T frag from lV, B = P^T frag via shfl)
        #pragma unroll
        for (int s = 0; s < 2; ++s) {
            short8 vf[4];
            #pragma unroll
            for (int i = 0; i < 4; ++i)
                vf[i] = *(const short8*)&lV[cur][(i * 16 + lr) * 64 + s * 32 + lq * 8];
            #pragma unroll
            for (int j = 0; j < 4; ++j) {
                int a0 = __shfl(pkd[2 * s][j][0], src0, 64);
                int c0 = __shfl(pkd[2 * s + 1][j][0], src0, 64);
                int a1 = __shfl(pkd[2 * s][j][1], src0, 64);
                int c1 = __shfl(pkd[2 * s + 1][j][1], src0, 64);
                int a2 = __shfl(pkd[2 * s][j][0], src1, 64);
                int c2 = __shfl(pkd[2 * s + 1][j][0], src1, 64);
                int a3 = __shfl(pkd[2 * s][j][1], src1, 64);
                int c3 = __shfl(pkd[2 * s + 1][j][1], src1, 64);
                int4v iv;
                iv[0] = hi ? c0 : a0;
                iv[1] = hi ? c1 : a1;
                iv[2] = hi ? c2 : a2;
                iv[3] = hi ? c3 : a3;
                short8 bq = __builtin_bit_cast(short8, iv);
                #pragma unroll
                for (int i = 0; i < 4; ++i)
                    oacc[i][j] = __builtin_amdgcn_mfma_f32_16x16x32_bf16(
                        vf[i], bq, oacc[i][j], 0, 0, 0);
            }
        }
        __syncthreads();   // drains prefetch vmcnt + releases buffer `cur`
    }

    // Epilogue: write unnormalized O^T partial (bf16) + l partial (fp32).
    unsigned short* op = opart + (size_t)half * 8192 * 1024;
    float* lp = lpart + (size_t)half * 8192 * 16;
    #pragma unroll
    for (int j = 0; j < 4; ++j) {
        l_i[j] += __shfl_xor(l_i[j], 16, 64);
        l_i[j] += __shfl_xor(l_i[j], 32, 64);
        const int q = q0 + j * 16 + lr;
        if (lq == 0)
            lp[(size_t)(b * 2048 + q) * 16 + h] = l_i[j];
        #pragma unroll
        for (int i = 0; i < 4; ++i) {
            int2 pk;
            pk.x = pack2bf(oacc[i][j][0], oacc[i][j][1]);
            pk.y = pack2bf(oacc[i][j][2], oacc[i][j][3]);
            *(int2*)&op[((size_t)(b * 2048 + q)) * 1024 + h * 64 + i * 16 + lq * 4] = pk;
        }
    }
}

// ---------------------------------------------------------------------------
// Combine split-K partials: oat = (O1 + O2) / (l1 + l2). Writes over O1's
// memory (same-thread read-then-write). Grid 8192 x 256.
// ---------------------------------------------------------------------------
__global__ __launch_bounds__(256)
void attn_combine(const unsigned short* __restrict__ o2,
                  const float* __restrict__ lpart,
                  unsigned short* o1_out) {
    const int row = blockIdx.x;
    const int t = threadIdx.x;
    const int h = t >> 4;   // 4 cols per thread, 64 cols per head
    const size_t base = (size_t)row * 1024 + t * 4;
    const float rl = 1.f / (lpart[(size_t)row * 16 + h] +
                            lpart[(size_t)(8192 + row) * 16 + h]);
    short4v a = *(const short4v*)&o1_out[base];
    short4v c = *(const short4v*)&o2[base];
    int2 pk;
    pk.x = pack2bf((bf2f((unsigned short)a[0]) + bf2f((unsigned short)c[0])) * rl,
                   (bf2f((unsigned short)a[1]) + bf2f((unsigned short)c[1])) * rl);
    pk.y = pack2bf((bf2f((unsigned short)a[2]) + bf2f((unsigned short)c[2])) * rl,
                   (bf2f((unsigned short)a[3]) + bf2f((unsigned short)c[3])) * rl);
    *(int2*)&o1_out[base] = pk;
}

// ---------------------------------------------------------------------------
// LN1: out_bf16 = LayerNorm(x_fp32 + res_bf16) * g + b   (g,b fp32)
// ---------------------------------------------------------------------------
__global__ __launch_bounds__(256)
void ln_f32_bf16(const float* __restrict__ x,
                 const unsigned short* __restrict__ res,
                 const float* __restrict__ g,
                 const float* __restrict__ bta,
                 unsigned short* __restrict__ out) {
    const int row = blockIdx.x;
    const int t = threadIdx.x;
    const size_t base = (size_t)row * 1024;

    float4 xv = *(const float4*)&x[base + t * 4];
    short4v rv = *(const short4v*)&res[base + t * 4];
    float v[4] = { xv.x + bf2f((unsigned short)rv[0]),
                   xv.y + bf2f((unsigned short)rv[1]),
                   xv.z + bf2f((unsigned short)rv[2]),
                   xv.w + bf2f((unsigned short)rv[3]) };
    float s = 0.f, s2 = 0.f;
    #pragma unroll
    for (int k = 0; k < 4; ++k) { s += v[k]; s2 += v[k] * v[k]; }
    #pragma unroll
    for (int off = 32; off > 0; off >>= 1) {
        s  += __shfl_xor(s, off, 64);
        s2 += __shfl_xor(s2, off, 64);
    }
    __shared__ float red[8];
    const int wave = t >> 6;
    if ((t & 63) == 0) { red[wave] = s; red[4 + wave] = s2; }
    __syncthreads();
    s  = red[0] + red[1] + red[2] + red[3];
    s2 = red[4] + red[5] + red[6] + red[7];
    const float mean = s * (1.f / 1024.f);
    const float var  = fmaxf(s2 * (1.f / 1024.f) - mean * mean, 0.f);
    const float inv  = rsqrtf(var + 1e-5f);

    short4v ov;
    #pragma unroll
    for (int k = 0; k < 4; ++k) {
        int c = t * 4 + k;
        ov[k] = (short)f2bf((v[k] - mean) * inv * g[c] + bta[c]);
    }
    *(short4v*)&out[base + t * 4] = ov;
}

// ---------------------------------------------------------------------------
// LN2: out_fp32 = LayerNorm(x_bf16 + res_bf16) * g + b
// ---------------------------------------------------------------------------
__global__ __launch_bounds__(256)
void ln_bf16_f32(const unsigned short* __restrict__ x,
                 const unsigned short* __restrict__ res,
                 const float* __restrict__ g,
                 const float* __restrict__ bta,
                 float* __restrict__ out) {
    const int row = blockIdx.x;
    const int t = threadIdx.x;
    const size_t base = (size_t)row * 1024;

    short4v xv = *(const short4v*)&x[base + t * 4];
    short4v rv = *(const short4v*)&res[base + t * 4];
    float v[4];
    float s = 0.f, s2 = 0.f;
    #pragma unroll
    for (int k = 0; k < 4; ++k) {
        v[k] = bf2f((unsigned short)xv[k]) + bf2f((unsigned short)rv[k]);
        s += v[k];
        s2 += v[k] * v[k];
    }
    #pragma unroll
    for (int off = 32; off > 0; off >>= 1) {
        s  += __shfl_xor(s, off, 64);
        s2 += __shfl_xor(s2, off, 64);
    }
    __shared__ float red[8];
    const int wave = t >> 6;
    if ((t & 63) == 0) { red[wave] = s; red[4 + wave] = s2; }
    __syncthreads();
    s  = red[0] + red[1] + red[2] + red[3];
    s2 = red[4] + red[5] + red[6] + red[7];
    const float mean = s * (1.f / 1024.f);
    const float var  = fmaxf(s2 * (1.f / 1024.f) - mean * mean, 0.f);
    const float inv  = rsqrtf(var + 1e-5f);

    float4 ov;
    ov.x = (v[0] - mean) * inv * g[t * 4 + 0] + bta[t * 4 + 0];
    ov.y = (v[1] - mean) * inv * g[t * 4 + 1] + bta[t * 4 + 1];
    ov.z = (v[2] - mean) * inv * g[t * 4 + 2] + bta[t * 4 + 2];
    ov.w = (v[3] - mean) * inv * g[t * 4 + 3] + bta[t * 4 + 3];
    *(float4*)&out[base + t * 4] = ov;
}

// ---------------------------------------------------------------------------
extern "C" void kernel_launch(void* const* d_in, const int* in_sizes, int n_in,
                              void* d_out, int out_size, void* d_ws, size_t ws_size,
                              hipStream_t stream) {
    const float* x      = (const float*)d_in[0];
    const float* qkv_w  = (const float*)d_in[1];
    const float* proj_w = (const float*)d_in[2];
    const float* proj_b = (const float*)d_in[3];
    const float* ln1_g  = (const float*)d_in[4];
    const float* ln1_b  = (const float*)d_in[5];
    const float* w1     = (const float*)d_in[6];
    const float* b1     = (const float*)d_in[7];
    const float* prelu  = (const float*)d_in[8];
    const float* w2     = (const float*)d_in[9];
    const float* b2     = (const float*)d_in[10];
    const float* ln2_g  = (const float*)d_in[11];
    const float* ln2_b  = (const float*)d_in[12];
    float* out = (float*)d_out;

    // Workspace (bf16 unless noted), peak 120 MB (validated):
    //  [0,6)    wqkvb -> lpart (fp32, 1 MB; wqkvb dead after qkv GEMM)
    //  [6,8)    wprojb    [8,16) w1b    [16,24) w2b
    //  [24,40)  xb -> vt (after qkv GEMM) -> pout (after combine) -> h2
    //  [40,88)  qkvb -> x1b[40,56)
    //  [88,104) opart half0 -> oat (combined, in place)
    //  [104,120) opart half1 -> h1 tail;  h1 = [56,120)
    char* ws = (char*)d_ws;
    const size_t MB = 1024 * 1024;
    unsigned short* wqkvb  = (unsigned short*)(ws);
    unsigned short* wprojb = (unsigned short*)(ws + 6 * MB);
    unsigned short* w1b    = (unsigned short*)(ws + 8 * MB);
    unsigned short* w2b    = (unsigned short*)(ws + 16 * MB);
    unsigned short* xb     = (unsigned short*)(ws + 24 * MB);
    unsigned short* vtb    = (unsigned short*)(ws + 24 * MB);  // alias xb (dead)
    unsigned short* qkvb   = (unsigned short*)(ws + 40 * MB);
    unsigned short* opart  = (unsigned short*)(ws + 88 * MB);  // 2x16 MB
    float*          lpart  = (float*)(ws);                     // 1 MB (wqkvb dead)
    unsigned short* oat    = (unsigned short*)(ws + 88 * MB);  // combined, in place
    unsigned short* pout   = (unsigned short*)(ws + 24 * MB);  // alias vt (dead)
    unsigned short* x1b    = (unsigned short*)(ws + 40 * MB);
    unsigned short* h1     = (unsigned short*)(ws + 56 * MB);
    unsigned short* h2     = (unsigned short*)(ws + 24 * MB);

    // 0) fp32 -> bf16 conversions
    cvt_f2b<<<8192, 256, 0, stream>>>(x,      xb);
    cvt_f2b<<<3072, 256, 0, stream>>>(qkv_w,  wqkvb);
    cvt_f2b<<<1024, 256, 0, stream>>>(proj_w, wprojb);
    cvt_f2b<<<4096, 256, 0, stream>>>(w1,     w1b);
    cvt_f2b<<<4096, 256, 0, stream>>>(w2,     w2b);

    // 1) qkv = x @ qkv_w^T  [8192,3072], Q columns (<1024) pre-scaled 0.125
    gemm_bt<<<dim3(64, 24), 256, 0, stream>>>(xb, wqkvb, nullptr, nullptr,
                                              qkvb, 3072, 1024, 1024);
    // 1b) V transpose -> vt[bh][d][key]  (xb dead)
    transpose_v<<<dim3(32, 64), 256, 0, stream>>>(qkvb, vtb);
    // 2) flash attention split-K x2 -> opart/lpart  (wqkvb dead -> lpart)
    attn_kernel<<<1024, 256, 0, stream>>>(qkvb, vtb, opart, lpart);
    // 2b) combine partials -> oat (in place over opart half0)
    attn_combine<<<8192, 256, 0, stream>>>(opart + (size_t)8192 * 1024, lpart, oat);
    // 3) proj -> pout (vt dead)
    gemm_bt<<<dim3(64, 8), 256, 0, stream>>>(oat, wprojb, proj_b, nullptr,
                                             pout, 1024, 1024, 0);
    // 4) x1b = LN(x + pout)  (qkvb dead)
    ln_f32_bf16<<<8192, 256, 0, stream>>>(x, pout, ln1_g, ln1_b, x1b);
    // 5) h1 = PReLU(x1b @ w1^T + b1)  [8192,4096]
    gemm_bt<<<dim3(64, 32), 256, 0, stream>>>(x1b, w1b, b1, prelu,
                                              h1, 4096, 1024, 0);
    // 6) h2 = h1 @ w2^T + b2  [8192,1024]
    gemm_bt<<<dim3(64, 8), 256, 0, stream>>>(h1, w2b, b2, nullptr,
                                             h2, 1024, 4096, 0);
    // 7) out = LN(x1b + h2)  (fp32 out)
    ln_bf16_f32<<<8192, 256, 0, stream>>>(x1b, h2, ln2_g, ln2_b, out);
}

// Round 10
// 661.460 us; speedup vs baseline: 1.0352x; 1.0352x over previous
//
#include <hip/hip_runtime.h>

// Inputs and output are FP32 (per the reference). Internal GEMM/attention
// compute is bf16 MFMA with fp32 accumulate; bf16 stored as unsigned short.

typedef __attribute__((ext_vector_type(8))) short short8;    // 8 bf16 = 1 MFMA A/B frag
typedef __attribute__((ext_vector_type(4))) short short4v;   // 4 bf16 = 8B vector
typedef __attribute__((ext_vector_type(4))) float floatx4;   // MFMA C/D frag
typedef __attribute__((ext_vector_type(4))) int int4v;

__device__ __forceinline__ float bf2f(unsigned short u) {
    return __uint_as_float(((unsigned int)u) << 16);
}
__device__ __forceinline__ unsigned short f2bf(float f) {
    unsigned int u = __float_as_uint(f);
    u += 0x7FFFu + ((u >> 16) & 1u);   // RNE
    return (unsigned short)(u >> 16);
}
__device__ __forceinline__ int pack2bf(float a, float b) {
    return (int)f2bf(a) | ((int)f2bf(b) << 16);
}

// Async global->LDS, 16 B per lane. LDS dest = wave-uniform base + lane*16.
__device__ __forceinline__ void async16(const unsigned short* g, unsigned short* l) {
    __builtin_amdgcn_global_load_lds(
        (const __attribute__((address_space(1))) unsigned int*)g,
        (__attribute__((address_space(3))) unsigned int*)l, 16, 0, 0);
}

// ---------------------------------------------------------------------------
// FP32 -> BF16 elementwise convert. grid = n/1024, block 256.
// ---------------------------------------------------------------------------
__global__ __launch_bounds__(256)
void cvt_f2b(const float* __restrict__ in, unsigned short* __restrict__ out) {
    const int i = (blockIdx.x * 256 + threadIdx.x) * 4;
    float4 v = *(const float4*)&in[i];
    short4v o;
    o[0] = (short)f2bf(v.x); o[1] = (short)f2bf(v.y);
    o[2] = (short)f2bf(v.z); o[3] = (short)f2bf(v.w);
    *(short4v*)&out[i] = o;
}

// ---------------------------------------------------------------------------
// C[M,N] = A[M,K] @ W[N,K]^T (+bias fp32) (+PReLU) (+0.125 scale on cols<qcols)
// bf16 in/out, fp32 acc. 128x128 tile, BK=64, 4 waves in 2x2. m97 staging.
// XCD swizzle: x = M-tile so linear id % 8 = m%8 -> A fetched once per XCD.
// ---------------------------------------------------------------------------
__global__ __launch_bounds__(256)
void gemm_bt(const unsigned short* __restrict__ A,
             const unsigned short* __restrict__ W,
             const float* __restrict__ bias,   // nullable, len N, fp32
             const float* __restrict__ prelu,  // nullable, scalar, fp32
             unsigned short* __restrict__ C,
             int N, int K, int qcols) {
    __shared__ alignas(16) unsigned short lA[128 * 64];
    __shared__ alignas(16) unsigned short lB[128 * 64];

    const int m0 = blockIdx.x * 128;   // x = M-tile (XCD locality for A)
    const int n0 = blockIdx.y * 128;
    const int tid  = threadIdx.x;
    const int lane = tid & 63;
    const int wave = tid >> 6;
    const int wm = (wave >> 1) * 64;
    const int wn = (wave & 1) * 64;
    const int lr = lane & 15;
    const int lq = lane >> 4;

    floatx4 acc[4][4] = {};

    for (int k0 = 0; k0 < K; k0 += 64) {
        #pragma unroll
        for (int it = 0; it < 4; ++it) {
            const int i = it * 256 + tid;
            const int row = i >> 3;
            const int col = (i & 7) << 3;
            unsigned short* dstA = &lA[(it * 256 + wave * 64) * 8];
            unsigned short* dstB = &lB[(it * 256 + wave * 64) * 8];
            async16(&A[(size_t)(m0 + row) * K + k0 + col], dstA);
            async16(&W[(size_t)(n0 + row) * K + k0 + col], dstB);
        }
        __syncthreads();
        #pragma unroll
        for (int s = 0; s < 2; ++s) {
            short8 af[4], bfr[4];
            #pragma unroll
            for (int i = 0; i < 4; ++i)
                af[i] = *(const short8*)&lA[(wm + i * 16 + lr) * 64 + s * 32 + lq * 8];
            #pragma unroll
            for (int j = 0; j < 4; ++j)
                bfr[j] = *(const short8*)&lB[(wn + j * 16 + lr) * 64 + s * 32 + lq * 8];
            #pragma unroll
            for (int i = 0; i < 4; ++i)
                #pragma unroll
                for (int j = 0; j < 4; ++j)
                    acc[i][j] = __builtin_amdgcn_mfma_f32_16x16x32_bf16(
                        af[i], bfr[j], acc[i][j], 0, 0, 0);
        }
        __syncthreads();
    }

    const bool has_prelu = (prelu != nullptr);
    const float slope = has_prelu ? prelu[0] : 0.f;
    #pragma unroll
    for (int j = 0; j < 4; ++j) {
        int gc = n0 + wn + j * 16 + lr;
        float bv = bias ? bias[gc] : 0.f;
        const float cscale = (gc < qcols) ? 0.125f : 1.f;
        #pragma unroll
        for (int i = 0; i < 4; ++i) {
            int gr = m0 + wm + i * 16 + lq * 4;
            #pragma unroll
            for (int r = 0; r < 4; ++r) {
                float v = acc[i][j][r] + bv;
                if (has_prelu && v < 0.f) v *= slope;
                C[(size_t)(gr + r) * N + gc] = f2bf(v * cscale);
            }
        }
    }
}

// ---------------------------------------------------------------------------
// V transpose: vt[(bh*64 + d)*2048 + key] = qkv[(b*2048+key)*3072 + 2048 + h*64 + d]
// ---------------------------------------------------------------------------
__global__ __launch_bounds__(256)
void transpose_v(const unsigned short* __restrict__ qkv,
                 unsigned short* __restrict__ vt) {
    const int kt = blockIdx.x;   // key tile 0..31
    const int bh = blockIdx.y;   // 0..63
    const int b = bh >> 4, h = bh & 15;
    __shared__ unsigned short tile[64 * 65];
    for (int t = threadIdx.x; t < 512; t += 256) {
        const int key = t >> 3, c8 = (t & 7) << 3;
        short8 v8 = *(const short8*)&qkv[((size_t)(b * 2048 + kt * 64 + key)) * 3072 +
                                         2048 + h * 64 + c8];
        #pragma unroll
        for (int e = 0; e < 8; ++e)
            tile[key * 65 + c8 + e] = (unsigned short)v8[e];
    }
    __syncthreads();
    for (int t = threadIdx.x; t < 512; t += 256) {
        const int d = t >> 3, k8 = (t & 7) << 3;
        short8 o;
        #pragma unroll
        for (int e = 0; e < 8; ++e)
            o[e] = (short)tile[(k8 + e) * 65 + d];
        *(short8*)&vt[((size_t)bh * 64 + d) * 2048 + kt * 64 + k8] = o;
    }
}

// ---------------------------------------------------------------------------
// Flash attention, S^T formulation, NO-MAX softmax. ONE WAVE PER BLOCK:
// each wave stages its own K/V (no inter-wave barrier coupling; __syncthreads
// on a 64-thread block is a single-wave no-op that just orders LDS vs VMEM).
// Grid 2048: id = qt*64 + bh -> id%8 = bh%8 (XCD locality for K/V).
// S^T = K·Q^T -> C-layout: q=lane&15, key=lq*4+reg.
// PV: O^T += V^T·P^T; P^T B-frags built from registers via shfl, with all
// 32 bpermutes of an s-step hoisted ahead of its 16 MFMAs (one lgkm wait).
// ---------------------------------------------------------------------------
__global__ __launch_bounds__(64)
void attn_kernel(const unsigned short* __restrict__ qkv,
                 const unsigned short* __restrict__ vt,
                 unsigned short* __restrict__ o_attn) {
    const int id = blockIdx.x;
    const int qt = id >> 6;     // 0..31
    const int bh = id & 63;     // 0..63
    const int b = bh >> 4, h = bh & 15;
    const int lane = threadIdx.x;
    const int lr = lane & 15;
    const int lq = lane >> 4;
    const int q0 = qt * 64;
    const size_t row0 = (size_t)(b * 2048) * 3072;

    __shared__ alignas(16) unsigned short lK[64 * 64];   // [key][d]
    __shared__ alignas(16) unsigned short lV[64 * 64];   // [d][key]

    // Q fragments (B-operand): [n = q = j*16+lr][k = s*32 + lq*8 + jj]
    short8 qf[4][2];
    #pragma unroll
    for (int j = 0; j < 4; ++j)
        #pragma unroll
        for (int s = 0; s < 2; ++s)
            qf[j][s] = *(const short8*)&qkv[row0 + (size_t)(q0 + j * 16 + lr) * 3072 +
                                            h * 64 + s * 32 + lq * 8];

    floatx4 oacc[4][4] = {};   // [dtile i][qtile j]: d=i*16+lq*4+r, q=j*16+lr
    float l_i[4] = {0.f, 0.f, 0.f, 0.f};

    const int src0 = lr + ((lq & 1) * 2) * 16;
    const int src1 = src0 + 16;
    const bool hi = (lq >> 1) != 0;

    const int srow = lane >> 3;          // staging row-within-8
    const int scol = (lane & 7) << 3;    // staging col

    for (int kc = 0; kc < 2048; kc += 64) {
        // Stage K [key][d] and V^T [d][key]: 8+8 async16 per wave.
        #pragma unroll
        for (int it = 0; it < 8; ++it) {
            const int row = it * 8 + srow;
            async16(&qkv[row0 + (size_t)(kc + row) * 3072 + 1024 + h * 64 + scol],
                    &lK[it * 512 + lane * 8]);
            async16(&vt[((size_t)bh * 64 + row) * 2048 + kc + scol],
                    &lV[it * 512 + lane * 8]);
        }
        __syncthreads();   // single-wave: orders VMEM->LDS vs ds_read

        // S^T = K·Q^T
        floatx4 sacc[4][4] = {};   // [keytile i][qtile j]: key=i*16+lq*4+r
        #pragma unroll
        for (int s = 0; s < 2; ++s) {
            short8 kf[4];
            #pragma unroll
            for (int i = 0; i < 4; ++i)
                kf[i] = *(const short8*)&lK[(i * 16 + lr) * 64 + s * 32 + lq * 8];
            #pragma unroll
            for (int i = 0; i < 4; ++i)
                #pragma unroll
                for (int j = 0; j < 4; ++j)
                    sacc[i][j] = __builtin_amdgcn_mfma_f32_16x16x32_bf16(
                        kf[i], qf[j][s], sacc[i][j], 0, 0, 0);
        }

        // P = exp(S), packed to bf16 pairs; l accumulated per-lane.
        int pkd[4][4][2];
        #pragma unroll
        for (int i = 0; i < 4; ++i)
            #pragma unroll
            for (int j = 0; j < 4; ++j) {
                const float e0 = __expf(sacc[i][j][0]);
                const float e1 = __expf(sacc[i][j][1]);
                const float e2 = __expf(sacc[i][j][2]);
                const float e3 = __expf(sacc[i][j][3]);
                l_i[j] += (e0 + e1) + (e2 + e3);
                pkd[i][j][0] = pack2bf(e0, e1);
                pkd[i][j][1] = pack2bf(e2, e3);
            }

        // O^T += V^T·P^T. All 32 bpermutes of the s-step hoisted before its
        // 16 MFMAs so the ds-latency is paid once, pipelined.
        #pragma unroll
        for (int s = 0; s < 2; ++s) {
            short8 vf[4];
            #pragma unroll
            for (int i = 0; i < 4; ++i)
                vf[i] = *(const short8*)&lV[(i * 16 + lr) * 64 + s * 32 + lq * 8];
            short8 bq[4];
            #pragma unroll
            for (int j = 0; j < 4; ++j) {
                int a0 = __shfl(pkd[2 * s][j][0], src0, 64);
                int c0 = __shfl(pkd[2 * s + 1][j][0], src0, 64);
                int a1 = __shfl(pkd[2 * s][j][1], src0, 64);
                int c1 = __shfl(pkd[2 * s + 1][j][1], src0, 64);
                int a2 = __shfl(pkd[2 * s][j][0], src1, 64);
                int c2 = __shfl(pkd[2 * s + 1][j][0], src1, 64);
                int a3 = __shfl(pkd[2 * s][j][1], src1, 64);
                int c3 = __shfl(pkd[2 * s + 1][j][1], src1, 64);
                int4v iv;
                iv[0] = hi ? c0 : a0;
                iv[1] = hi ? c1 : a1;
                iv[2] = hi ? c2 : a2;
                iv[3] = hi ? c3 : a3;
                bq[j] = __builtin_bit_cast(short8, iv);
            }
            #pragma unroll
            for (int j = 0; j < 4; ++j)
                #pragma unroll
                for (int i = 0; i < 4; ++i)
                    oacc[i][j] = __builtin_amdgcn_mfma_f32_16x16x32_bf16(
                        vf[i], bq[j], oacc[i][j], 0, 0, 0);
        }
        __syncthreads();   // single-wave: LDS reads of this chunk drained
    }

    // Epilogue: reduce l across the 4 lq groups, normalize, packed stores.
    #pragma unroll
    for (int j = 0; j < 4; ++j) {
        l_i[j] += __shfl_xor(l_i[j], 16, 64);
        l_i[j] += __shfl_xor(l_i[j], 32, 64);
        const float rl = 1.f / l_i[j];
        const int q = q0 + j * 16 + lr;
        #pragma unroll
        for (int i = 0; i < 4; ++i) {
            int2 pk;
            pk.x = pack2bf(oacc[i][j][0] * rl, oacc[i][j][1] * rl);
            pk.y = pack2bf(oacc[i][j][2] * rl, oacc[i][j][3] * rl);
            *(int2*)&o_attn[((size_t)(b * 2048 + q)) * 1024 + h * 64 + i * 16 + lq * 4] = pk;
        }
    }
}

// ---------------------------------------------------------------------------
// LN1: out_bf16 = LayerNorm(x_fp32 + res_bf16) * g + b   (g,b fp32)
// ---------------------------------------------------------------------------
__global__ __launch_bounds__(256)
void ln_f32_bf16(const float* __restrict__ x,
                 const unsigned short* __restrict__ res,
                 const float* __restrict__ g,
                 const float* __restrict__ bta,
                 unsigned short* __restrict__ out) {
    const int row = blockIdx.x;
    const int t = threadIdx.x;
    const size_t base = (size_t)row * 1024;

    float4 xv = *(const float4*)&x[base + t * 4];
    short4v rv = *(const short4v*)&res[base + t * 4];
    float v[4] = { xv.x + bf2f((unsigned short)rv[0]),
                   xv.y + bf2f((unsigned short)rv[1]),
                   xv.z + bf2f((unsigned short)rv[2]),
                   xv.w + bf2f((unsigned short)rv[3]) };
    float s = 0.f, s2 = 0.f;
    #pragma unroll
    for (int k = 0; k < 4; ++k) { s += v[k]; s2 += v[k] * v[k]; }
    #pragma unroll
    for (int off = 32; off > 0; off >>= 1) {
        s  += __shfl_xor(s, off, 64);
        s2 += __shfl_xor(s2, off, 64);
    }
    __shared__ float red[8];
    const int wave = t >> 6;
    if ((t & 63) == 0) { red[wave] = s; red[4 + wave] = s2; }
    __syncthreads();
    s  = red[0] + red[1] + red[2] + red[3];
    s2 = red[4] + red[5] + red[6] + red[7];
    const float mean = s * (1.f / 1024.f);
    const float var  = fmaxf(s2 * (1.f / 1024.f) - mean * mean, 0.f);
    const float inv  = rsqrtf(var + 1e-5f);

    short4v ov;
    #pragma unroll
    for (int k = 0; k < 4; ++k) {
        int c = t * 4 + k;
        ov[k] = (short)f2bf((v[k] - mean) * inv * g[c] + bta[c]);
    }
    *(short4v*)&out[base + t * 4] = ov;
}

// ---------------------------------------------------------------------------
// LN2: out_fp32 = LayerNorm(x_bf16 + res_bf16) * g + b
// ---------------------------------------------------------------------------
__global__ __launch_bounds__(256)
void ln_bf16_f32(const unsigned short* __restrict__ x,
                 const unsigned short* __restrict__ res,
                 const float* __restrict__ g,
                 const float* __restrict__ bta,
                 float* __restrict__ out) {
    const int row = blockIdx.x;
    const int t = threadIdx.x;
    const size_t base = (size_t)row * 1024;

    short4v xv = *(const short4v*)&x[base + t * 4];
    short4v rv = *(const short4v*)&res[base + t * 4];
    float v[4];
    float s = 0.f, s2 = 0.f;
    #pragma unroll
    for (int k = 0; k < 4; ++k) {
        v[k] = bf2f((unsigned short)xv[k]) + bf2f((unsigned short)rv[k]);
        s += v[k];
        s2 += v[k] * v[k];
    }
    #pragma unroll
    for (int off = 32; off > 0; off >>= 1) {
        s  += __shfl_xor(s, off, 64);
        s2 += __shfl_xor(s2, off, 64);
    }
    __shared__ float red[8];
    const int wave = t >> 6;
    if ((t & 63) == 0) { red[wave] = s; red[4 + wave] = s2; }
    __syncthreads();
    s  = red[0] + red[1] + red[2] + red[3];
    s2 = red[4] + red[5] + red[6] + red[7];
    const float mean = s * (1.f / 1024.f);
    const float var  = fmaxf(s2 * (1.f / 1024.f) - mean * mean, 0.f);
    const float inv  = rsqrtf(var + 1e-5f);

    float4 ov;
    ov.x = (v[0] - mean) * inv * g[t * 4 + 0] + bta[t * 4 + 0];
    ov.y = (v[1] - mean) * inv * g[t * 4 + 1] + bta[t * 4 + 1];
    ov.z = (v[2] - mean) * inv * g[t * 4 + 2] + bta[t * 4 + 2];
    ov.w = (v[3] - mean) * inv * g[t * 4 + 3] + bta[t * 4 + 3];
    *(float4*)&out[base + t * 4] = ov;
}

// ---------------------------------------------------------------------------
extern "C" void kernel_launch(void* const* d_in, const int* in_sizes, int n_in,
                              void* d_out, int out_size, void* d_ws, size_t ws_size,
                              hipStream_t stream) {
    const float* x      = (const float*)d_in[0];
    const float* qkv_w  = (const float*)d_in[1];
    const float* proj_w = (const float*)d_in[2];
    const float* proj_b = (const float*)d_in[3];
    const float* ln1_g  = (const float*)d_in[4];
    const float* ln1_b  = (const float*)d_in[5];
    const float* w1     = (const float*)d_in[6];
    const float* b1     = (const float*)d_in[7];
    const float* prelu  = (const float*)d_in[8];
    const float* w2     = (const float*)d_in[9];
    const float* b2     = (const float*)d_in[10];
    const float* ln2_g  = (const float*)d_in[11];
    const float* ln2_b  = (const float*)d_in[12];
    float* out = (float*)d_out;

    // Workspace (bf16 buffers), peak 120 MB (validated):
    //  [0,24)   weights (qkv 6 | proj 2 | w1 8 | w2 8)
    //  [24,40)  xb -> vt (after qkv GEMM) -> pout (after attn) -> h2
    //  [40,88)  qkvb -> x1b[40,56)       [88,104) oat       h1 = [56,120)
    char* ws = (char*)d_ws;
    const size_t MB = 1024 * 1024;
    unsigned short* wqkvb  = (unsigned short*)(ws);
    unsigned short* wprojb = (unsigned short*)(ws + 6 * MB);
    unsigned short* w1b    = (unsigned short*)(ws + 8 * MB);
    unsigned short* w2b    = (unsigned short*)(ws + 16 * MB);
    unsigned short* xb     = (unsigned short*)(ws + 24 * MB);
    unsigned short* vtb    = (unsigned short*)(ws + 24 * MB);  // alias xb (dead)
    unsigned short* qkvb   = (unsigned short*)(ws + 40 * MB);
    unsigned short* oat    = (unsigned short*)(ws + 88 * MB);
    unsigned short* pout   = (unsigned short*)(ws + 24 * MB);  // alias vt (dead)
    unsigned short* x1b    = (unsigned short*)(ws + 40 * MB);
    unsigned short* h1     = (unsigned short*)(ws + 56 * MB);
    unsigned short* h2     = (unsigned short*)(ws + 24 * MB);

    // 0) fp32 -> bf16 conversions
    cvt_f2b<<<8192, 256, 0, stream>>>(x,      xb);
    cvt_f2b<<<3072, 256, 0, stream>>>(qkv_w,  wqkvb);
    cvt_f2b<<<1024, 256, 0, stream>>>(proj_w, wprojb);
    cvt_f2b<<<4096, 256, 0, stream>>>(w1,     w1b);
    cvt_f2b<<<4096, 256, 0, stream>>>(w2,     w2b);

    // 1) qkv = x @ qkv_w^T  [8192,3072], Q columns (<1024) pre-scaled 0.125
    gemm_bt<<<dim3(64, 24), 256, 0, stream>>>(xb, wqkvb, nullptr, nullptr,
                                              qkvb, 3072, 1024, 1024);
    // 1b) V transpose -> vt[bh][d][key]  (xb dead)
    transpose_v<<<dim3(32, 64), 256, 0, stream>>>(qkvb, vtb);
    // 2) flash attention -> oat [8192,1024]  (1-wave blocks, XCD = bh%8)
    attn_kernel<<<2048, 64, 0, stream>>>(qkvb, vtb, oat);
    // 3) proj -> pout (vt dead)
    gemm_bt<<<dim3(64, 8), 256, 0, stream>>>(oat, wprojb, proj_b, nullptr,
                                             pout, 1024, 1024, 0);
    // 4) x1b = LN(x + pout)  (qkvb dead)
    ln_f32_bf16<<<8192, 256, 0, stream>>>(x, pout, ln1_g, ln1_b, x1b);
    // 5) h1 = PReLU(x1b @ w1^T + b1)  [8192,4096]
    gemm_bt<<<dim3(64, 32), 256, 0, stream>>>(x1b, w1b, b1, prelu,
                                              h1, 4096, 1024, 0);
    // 6) h2 = h1 @ w2^T + b2  [8192,1024]
    gemm_bt<<<dim3(64, 8), 256, 0, stream>>>(h1, w2b, b2, nullptr,
                                             h2, 1024, 4096, 0);
    // 7) out = LN(x1b + h2)  (fp32 out)
    ln_bf16_f32<<<8192, 256, 0, stream>>>(x1b, h2, ln2_g, ln2_b, out);
}

// Round 11
// 648.428 us; speedup vs baseline: 1.0560x; 1.0201x over previous
//
#include <hip/hip_runtime.h>

// Inputs and output are FP32 (per the reference). Internal GEMM/attention
// compute is bf16 MFMA with fp32 accumulate; bf16 stored as unsigned short.

typedef __attribute__((ext_vector_type(8))) short short8;    // 8 bf16 = 1 MFMA A/B frag
typedef __attribute__((ext_vector_type(4))) short short4v;   // 4 bf16 = 8B vector
typedef __attribute__((ext_vector_type(4))) float floatx4;   // MFMA C/D frag
typedef __attribute__((ext_vector_type(4))) int int4v;

__device__ __forceinline__ float bf2f(unsigned short u) {
    return __uint_as_float(((unsigned int)u) << 16);
}
__device__ __forceinline__ unsigned short f2bf(float f) {
    unsigned int u = __float_as_uint(f);
    u += 0x7FFFu + ((u >> 16) & 1u);   // RNE
    return (unsigned short)(u >> 16);
}
__device__ __forceinline__ int pack2bf(float a, float b) {
    return (int)f2bf(a) | ((int)f2bf(b) << 16);
}

// Async global->LDS, 16 B per lane. LDS dest = wave-uniform base + lane*16.
__device__ __forceinline__ void async16(const unsigned short* g, unsigned short* l) {
    __builtin_amdgcn_global_load_lds(
        (const __attribute__((address_space(1))) unsigned int*)g,
        (__attribute__((address_space(3))) unsigned int*)l, 16, 0, 0);
}

// ---------------------------------------------------------------------------
// FP32 -> BF16 elementwise convert. grid = n/1024, block 256.
// ---------------------------------------------------------------------------
__global__ __launch_bounds__(256)
void cvt_f2b(const float* __restrict__ in, unsigned short* __restrict__ out) {
    const int i = (blockIdx.x * 256 + threadIdx.x) * 4;
    float4 v = *(const float4*)&in[i];
    short4v o;
    o[0] = (short)f2bf(v.x); o[1] = (short)f2bf(v.y);
    o[2] = (short)f2bf(v.z); o[3] = (short)f2bf(v.w);
    *(short4v*)&out[i] = o;
}

// ---------------------------------------------------------------------------
// C[M,N] = A[M,K] @ W[N,K]^T (+bias fp32) (+PReLU) (+0.125 scale on cols<qcols)
// bf16 in/out, fp32 acc. 128x128 tile, BK=64, 4 waves in 2x2. m97 staging.
// XCD swizzle: x = M-tile so linear id % 8 = m%8 -> A fetched once per XCD.
// ---------------------------------------------------------------------------
__global__ __launch_bounds__(256)
void gemm_bt(const unsigned short* __restrict__ A,
             const unsigned short* __restrict__ W,
             const float* __restrict__ bias,   // nullable, len N, fp32
             const float* __restrict__ prelu,  // nullable, scalar, fp32
             unsigned short* __restrict__ C,
             int N, int K, int qcols) {
    __shared__ alignas(16) unsigned short lA[128 * 64];
    __shared__ alignas(16) unsigned short lB[128 * 64];

    const int m0 = blockIdx.x * 128;   // x = M-tile (XCD locality for A)
    const int n0 = blockIdx.y * 128;
    const int tid  = threadIdx.x;
    const int lane = tid & 63;
    const int wave = tid >> 6;
    const int wm = (wave >> 1) * 64;
    const int wn = (wave & 1) * 64;
    const int lr = lane & 15;
    const int lq = lane >> 4;

    floatx4 acc[4][4] = {};

    for (int k0 = 0; k0 < K; k0 += 64) {
        #pragma unroll
        for (int it = 0; it < 4; ++it) {
            const int i = it * 256 + tid;
            const int row = i >> 3;
            const int col = (i & 7) << 3;
            unsigned short* dstA = &lA[(it * 256 + wave * 64) * 8];
            unsigned short* dstB = &lB[(it * 256 + wave * 64) * 8];
            async16(&A[(size_t)(m0 + row) * K + k0 + col], dstA);
            async16(&W[(size_t)(n0 + row) * K + k0 + col], dstB);
        }
        __syncthreads();
        #pragma unroll
        for (int s = 0; s < 2; ++s) {
            short8 af[4], bfr[4];
            #pragma unroll
            for (int i = 0; i < 4; ++i)
                af[i] = *(const short8*)&lA[(wm + i * 16 + lr) * 64 + s * 32 + lq * 8];
            #pragma unroll
            for (int j = 0; j < 4; ++j)
                bfr[j] = *(const short8*)&lB[(wn + j * 16 + lr) * 64 + s * 32 + lq * 8];
            #pragma unroll
            for (int i = 0; i < 4; ++i)
                #pragma unroll
                for (int j = 0; j < 4; ++j)
                    acc[i][j] = __builtin_amdgcn_mfma_f32_16x16x32_bf16(
                        af[i], bfr[j], acc[i][j], 0, 0, 0);
        }
        __syncthreads();
    }

    const bool has_prelu = (prelu != nullptr);
    const float slope = has_prelu ? prelu[0] : 0.f;
    #pragma unroll
    for (int j = 0; j < 4; ++j) {
        int gc = n0 + wn + j * 16 + lr;
        float bv = bias ? bias[gc] : 0.f;
        const float cscale = (gc < qcols) ? 0.125f : 1.f;
        #pragma unroll
        for (int i = 0; i < 4; ++i) {
            int gr = m0 + wm + i * 16 + lq * 4;
            #pragma unroll
            for (int r = 0; r < 4; ++r) {
                float v = acc[i][j][r] + bv;
                if (has_prelu && v < 0.f) v *= slope;
                C[(size_t)(gr + r) * N + gc] = f2bf(v * cscale);
            }
        }
    }
}

// ---------------------------------------------------------------------------
// V transpose: vt[(bh*64 + d)*2048 + key] = qkv[(b*2048+key)*3072 + 2048 + h*64 + d]
// ---------------------------------------------------------------------------
__global__ __launch_bounds__(256)
void transpose_v(const unsigned short* __restrict__ qkv,
                 unsigned short* __restrict__ vt) {
    const int kt = blockIdx.x;   // key tile 0..31
    const int bh = blockIdx.y;   // 0..63
    const int b = bh >> 4, h = bh & 15;
    __shared__ unsigned short tile[64 * 65];
    for (int t = threadIdx.x; t < 512; t += 256) {
        const int key = t >> 3, c8 = (t & 7) << 3;
        short8 v8 = *(const short8*)&qkv[((size_t)(b * 2048 + kt * 64 + key)) * 3072 +
                                         2048 + h * 64 + c8];
        #pragma unroll
        for (int e = 0; e < 8; ++e)
            tile[key * 65 + c8 + e] = (unsigned short)v8[e];
    }
    __syncthreads();
    for (int t = threadIdx.x; t < 512; t += 256) {
        const int d = t >> 3, k8 = (t & 7) << 3;
        short8 o;
        #pragma unroll
        for (int e = 0; e < 8; ++e)
            o[e] = (short)tile[(k8 + e) * 65 + d];
        *(short8*)&vt[((size_t)bh * 64 + d) * 2048 + kt * 64 + k8] = o;
    }
}

// ---------------------------------------------------------------------------
// Flash attention, S^T formulation, NO-MAX softmax. ONE WAVE PER BLOCK with
// TRUE async double-buffer: no barrier anywhere in the K-loop. K/V staged
// 2-deep via async16; ordering enforced with raw `s_waitcnt vmcnt(16)` —
// waits for the current buffer's 16 loads while the next buffer's 16 stay
// in flight (the AITER pattern the barrier structure cannot express).
// Grid 2048: id = qt*64 + bh -> id%8 = bh%8 (XCD locality for K/V).
// ---------------------------------------------------------------------------
__global__ __launch_bounds__(64)
void attn_kernel(const unsigned short* __restrict__ qkv,
                 const unsigned short* __restrict__ vt,
                 unsigned short* __restrict__ o_attn) {
    const int id = blockIdx.x;
    const int qt = id >> 6;     // 0..31
    const int bh = id & 63;     // 0..63
    const int b = bh >> 4, h = bh & 15;
    const int lane = threadIdx.x;
    const int lr = lane & 15;
    const int lq = lane >> 4;
    const int q0 = qt * 64;
    const size_t row0 = (size_t)(b * 2048) * 3072;

    __shared__ alignas(16) unsigned short lK[2][64 * 64];   // [key][d]
    __shared__ alignas(16) unsigned short lV[2][64 * 64];   // [d][key]

    // Q fragments (B-operand): [n = q = j*16+lr][k = s*32 + lq*8 + jj]
    short8 qf[4][2];
    #pragma unroll
    for (int j = 0; j < 4; ++j)
        #pragma unroll
        for (int s = 0; s < 2; ++s)
            qf[j][s] = *(const short8*)&qkv[row0 + (size_t)(q0 + j * 16 + lr) * 3072 +
                                            h * 64 + s * 32 + lq * 8];

    floatx4 oacc[4][4] = {};   // [dtile i][qtile j]: d=i*16+lq*4+r, q=j*16+lr
    float l_i[4] = {0.f, 0.f, 0.f, 0.f};

    const int src0 = lr + ((lq & 1) * 2) * 16;
    const int src1 = src0 + 16;
    const bool hi = (lq >> 1) != 0;

    const int srow = lane >> 3;          // staging row-within-8
    const int scol = (lane & 7) << 3;    // staging col

    // Stage one 64-key chunk into buffer bi: 8 K-loads + 8 V-loads.
    auto stage = [&](int bi, int kc) {
        #pragma unroll
        for (int it = 0; it < 8; ++it) {
            const int row = it * 8 + srow;
            async16(&qkv[row0 + (size_t)(kc + row) * 3072 + 1024 + h * 64 + scol],
                    &lK[bi][it * 512 + lane * 8]);
            async16(&vt[((size_t)bh * 64 + row) * 2048 + kc + scol],
                    &lV[bi][it * 512 + lane * 8]);
        }
    };

    // Drain Q loads so vmcnt arithmetic below counts only staging loads.
    asm volatile("s_waitcnt vmcnt(0)" ::: "memory");
    stage(0, 0);
    stage(1, 64);

    #pragma unroll 1
    for (int c = 0; c < 32; ++c) {
        const int cur = c & 1;
        // Current buffer's 16 loads complete; next buffer's 16 stay in flight.
        if (c < 30) {
            asm volatile("s_waitcnt vmcnt(16)" ::: "memory");
        } else {
            asm volatile("s_waitcnt vmcnt(0)" ::: "memory");
        }

        // S^T = K·Q^T
        floatx4 sacc[4][4] = {};   // [keytile i][qtile j]: key=i*16+lq*4+r
        #pragma unroll
        for (int s = 0; s < 2; ++s) {
            short8 kf[4];
            #pragma unroll
            for (int i = 0; i < 4; ++i)
                kf[i] = *(const short8*)&lK[cur][(i * 16 + lr) * 64 + s * 32 + lq * 8];
            #pragma unroll
            for (int i = 0; i < 4; ++i)
                #pragma unroll
                for (int j = 0; j < 4; ++j)
                    sacc[i][j] = __builtin_amdgcn_mfma_f32_16x16x32_bf16(
                        kf[i], qf[j][s], sacc[i][j], 0, 0, 0);
        }

        // P = exp(S), packed to bf16 pairs; l accumulated per-lane.
        int pkd[4][4][2];
        #pragma unroll
        for (int i = 0; i < 4; ++i)
            #pragma unroll
            for (int j = 0; j < 4; ++j) {
                const float e0 = __expf(sacc[i][j][0]);
                const float e1 = __expf(sacc[i][j][1]);
                const float e2 = __expf(sacc[i][j][2]);
                const float e3 = __expf(sacc[i][j][3]);
                l_i[j] += (e0 + e1) + (e2 + e3);
                pkd[i][j][0] = pack2bf(e0, e1);
                pkd[i][j][1] = pack2bf(e2, e3);
            }

        // O^T += V^T·P^T. 32 bpermutes per s-step hoisted ahead of its MFMAs.
        #pragma unroll
        for (int s = 0; s < 2; ++s) {
            short8 vf[4];
            #pragma unroll
            for (int i = 0; i < 4; ++i)
                vf[i] = *(const short8*)&lV[cur][(i * 16 + lr) * 64 + s * 32 + lq * 8];
            short8 bq[4];
            #pragma unroll
            for (int j = 0; j < 4; ++j) {
                int a0 = __shfl(pkd[2 * s][j][0], src0, 64);
                int c0 = __shfl(pkd[2 * s + 1][j][0], src0, 64);
                int a1 = __shfl(pkd[2 * s][j][1], src0, 64);
                int c1 = __shfl(pkd[2 * s + 1][j][1], src0, 64);
                int a2 = __shfl(pkd[2 * s][j][0], src1, 64);
                int c2 = __shfl(pkd[2 * s + 1][j][0], src1, 64);
                int a3 = __shfl(pkd[2 * s][j][1], src1, 64);
                int c3 = __shfl(pkd[2 * s + 1][j][1], src1, 64);
                int4v iv;
                iv[0] = hi ? c0 : a0;
                iv[1] = hi ? c1 : a1;
                iv[2] = hi ? c2 : a2;
                iv[3] = hi ? c3 : a3;
                bq[j] = __builtin_bit_cast(short8, iv);
            }
            #pragma unroll
            for (int j = 0; j < 4; ++j)
                #pragma unroll
                for (int i = 0; i < 4; ++i)
                    oacc[i][j] = __builtin_amdgcn_mfma_f32_16x16x32_bf16(
                        vf[i], bq[j], oacc[i][j], 0, 0, 0);
        }

        // Refill this buffer with chunk c+2 (reads of `cur` are consumed by
        // the MFMAs above; compiler's lgkm waits have already ordered them).
        if (c + 2 < 32) {
            asm volatile("" ::: "memory");   // keep stage after the reads
            stage(cur, (c + 2) * 64);
        }
    }

    // Epilogue: reduce l across the 4 lq groups, normalize, packed stores.
    #pragma unroll
    for (int j = 0; j < 4; ++j) {
        l_i[j] += __shfl_xor(l_i[j], 16, 64);
        l_i[j] += __shfl_xor(l_i[j], 32, 64);
        const float rl = 1.f / l_i[j];
        const int q = q0 + j * 16 + lr;
        #pragma unroll
        for (int i = 0; i < 4; ++i) {
            int2 pk;
            pk.x = pack2bf(oacc[i][j][0] * rl, oacc[i][j][1] * rl);
            pk.y = pack2bf(oacc[i][j][2] * rl, oacc[i][j][3] * rl);
            *(int2*)&o_attn[((size_t)(b * 2048 + q)) * 1024 + h * 64 + i * 16 + lq * 4] = pk;
        }
    }
}

// ---------------------------------------------------------------------------
// LN1: out_bf16 = LayerNorm(x_fp32 + res_bf16) * g + b   (g,b fp32)
// ---------------------------------------------------------------------------
__global__ __launch_bounds__(256)
void ln_f32_bf16(const float* __restrict__ x,
                 const unsigned short* __restrict__ res,
                 const float* __restrict__ g,
                 const float* __restrict__ bta,
                 unsigned short* __restrict__ out) {
    const int row = blockIdx.x;
    const int t = threadIdx.x;
    const size_t base = (size_t)row * 1024;

    float4 xv = *(const float4*)&x[base + t * 4];
    short4v rv = *(const short4v*)&res[base + t * 4];
    float v[4] = { xv.x + bf2f((unsigned short)rv[0]),
                   xv.y + bf2f((unsigned short)rv[1]),
                   xv.z + bf2f((unsigned short)rv[2]),
                   xv.w + bf2f((unsigned short)rv[3]) };
    float s = 0.f, s2 = 0.f;
    #pragma unroll
    for (int k = 0; k < 4; ++k) { s += v[k]; s2 += v[k] * v[k]; }
    #pragma unroll
    for (int off = 32; off > 0; off >>= 1) {
        s  += __shfl_xor(s, off, 64);
        s2 += __shfl_xor(s2, off, 64);
    }
    __shared__ float red[8];
    const int wave = t >> 6;
    if ((t & 63) == 0) { red[wave] = s; red[4 + wave] = s2; }
    __syncthreads();
    s  = red[0] + red[1] + red[2] + red[3];
    s2 = red[4] + red[5] + red[6] + red[7];
    const float mean = s * (1.f / 1024.f);
    const float var  = fmaxf(s2 * (1.f / 1024.f) - mean * mean, 0.f);
    const float inv  = rsqrtf(var + 1e-5f);

    short4v ov;
    #pragma unroll
    for (int k = 0; k < 4; ++k) {
        int c = t * 4 + k;
        ov[k] = (short)f2bf((v[k] - mean) * inv * g[c] + bta[c]);
    }
    *(short4v*)&out[base + t * 4] = ov;
}

// ---------------------------------------------------------------------------
// LN2: out_fp32 = LayerNorm(x_bf16 + res_bf16) * g + b
// ---------------------------------------------------------------------------
__global__ __launch_bounds__(256)
void ln_bf16_f32(const unsigned short* __restrict__ x,
                 const unsigned short* __restrict__ res,
                 const float* __restrict__ g,
                 const float* __restrict__ bta,
                 float* __restrict__ out) {
    const int row = blockIdx.x;
    const int t = threadIdx.x;
    const size_t base = (size_t)row * 1024;

    short4v xv = *(const short4v*)&x[base + t * 4];
    short4v rv = *(const short4v*)&res[base + t * 4];
    float v[4];
    float s = 0.f, s2 = 0.f;
    #pragma unroll
    for (int k = 0; k < 4; ++k) {
        v[k] = bf2f((unsigned short)xv[k]) + bf2f((unsigned short)rv[k]);
        s += v[k];
        s2 += v[k] * v[k];
    }
    #pragma unroll
    for (int off = 32; off > 0; off >>= 1) {
        s  += __shfl_xor(s, off, 64);
        s2 += __shfl_xor(s2, off, 64);
    }
    __shared__ float red[8];
    const int wave = t >> 6;
    if ((t & 63) == 0) { red[wave] = s; red[4 + wave] = s2; }
    __syncthreads();
    s  = red[0] + red[1] + red[2] + red[3];
    s2 = red[4] + red[5] + red[6] + red[7];
    const float mean = s * (1.f / 1024.f);
    const float var  = fmaxf(s2 * (1.f / 1024.f) - mean * mean, 0.f);
    const float inv  = rsqrtf(var + 1e-5f);

    float4 ov;
    ov.x = (v[0] - mean) * inv * g[t * 4 + 0] + bta[t * 4 + 0];
    ov.y = (v[1] - mean) * inv * g[t * 4 + 1] + bta[t * 4 + 1];
    ov.z = (v[2] - mean) * inv * g[t * 4 + 2] + bta[t * 4 + 2];
    ov.w = (v[3] - mean) * inv * g[t * 4 + 3] + bta[t * 4 + 3];
    *(float4*)&out[base + t * 4] = ov;
}

// ---------------------------------------------------------------------------
extern "C" void kernel_launch(void* const* d_in, const int* in_sizes, int n_in,
                              void* d_out, int out_size, void* d_ws, size_t ws_size,
                              hipStream_t stream) {
    const float* x      = (const float*)d_in[0];
    const float* qkv_w  = (const float*)d_in[1];
    const float* proj_w = (const float*)d_in[2];
    const float* proj_b = (const float*)d_in[3];
    const float* ln1_g  = (const float*)d_in[4];
    const float* ln1_b  = (const float*)d_in[5];
    const float* w1     = (const float*)d_in[6];
    const float* b1     = (const float*)d_in[7];
    const float* prelu  = (const float*)d_in[8];
    const float* w2     = (const float*)d_in[9];
    const float* b2     = (const float*)d_in[10];
    const float* ln2_g  = (const float*)d_in[11];
    const float* ln2_b  = (const float*)d_in[12];
    float* out = (float*)d_out;

    // Workspace (bf16 buffers), peak 120 MB (validated):
    //  [0,24)   weights (qkv 6 | proj 2 | w1 8 | w2 8)
    //  [24,40)  xb -> vt (after qkv GEMM) -> pout (after attn) -> h2
    //  [40,88)  qkvb -> x1b[40,56)       [88,104) oat       h1 = [56,120)
    char* ws = (char*)d_ws;
    const size_t MB = 1024 * 1024;
    unsigned short* wqkvb  = (unsigned short*)(ws);
    unsigned short* wprojb = (unsigned short*)(ws + 6 * MB);
    unsigned short* w1b    = (unsigned short*)(ws + 8 * MB);
    unsigned short* w2b    = (unsigned short*)(ws + 16 * MB);
    unsigned short* xb     = (unsigned short*)(ws + 24 * MB);
    unsigned short* vtb    = (unsigned short*)(ws + 24 * MB);  // alias xb (dead)
    unsigned short* qkvb   = (unsigned short*)(ws + 40 * MB);
    unsigned short* oat    = (unsigned short*)(ws + 88 * MB);
    unsigned short* pout   = (unsigned short*)(ws + 24 * MB);  // alias vt (dead)
    unsigned short* x1b    = (unsigned short*)(ws + 40 * MB);
    unsigned short* h1     = (unsigned short*)(ws + 56 * MB);
    unsigned short* h2     = (unsigned short*)(ws + 24 * MB);

    // 0) fp32 -> bf16 conversions
    cvt_f2b<<<8192, 256, 0, stream>>>(x,      xb);
    cvt_f2b<<<3072, 256, 0, stream>>>(qkv_w,  wqkvb);
    cvt_f2b<<<1024, 256, 0, stream>>>(proj_w, wprojb);
    cvt_f2b<<<4096, 256, 0, stream>>>(w1,     w1b);
    cvt_f2b<<<4096, 256, 0, stream>>>(w2,     w2b);

    // 1) qkv = x @ qkv_w^T  [8192,3072], Q columns (<1024) pre-scaled 0.125
    gemm_bt<<<dim3(64, 24), 256, 0, stream>>>(xb, wqkvb, nullptr, nullptr,
                                              qkvb, 3072, 1024, 1024);
    // 1b) V transpose -> vt[bh][d][key]  (xb dead)
    transpose_v<<<dim3(32, 64), 256, 0, stream>>>(qkvb, vtb);
    // 2) flash attention -> oat [8192,1024]  (1-wave blocks, async dbuf)
    attn_kernel<<<2048, 64, 0, stream>>>(qkvb, vtb, oat);
    // 3) proj -> pout (vt dead)
    gemm_bt<<<dim3(64, 8), 256, 0, stream>>>(oat, wprojb, proj_b, nullptr,
                                             pout, 1024, 1024, 0);
    // 4) x1b = LN(x + pout)  (qkvb dead)
    ln_f32_bf16<<<8192, 256, 0, stream>>>(x, pout, ln1_g, ln1_b, x1b);
    // 5) h1 = PReLU(x1b @ w1^T + b1)  [8192,4096]
    gemm_bt<<<dim3(64, 32), 256, 0, stream>>>(x1b, w1b, b1, prelu,
                                              h1, 4096, 1024, 0);
    // 6) h2 = h1 @ w2^T + b2  [8192,1024]
    gemm_bt<<<dim3(64, 8), 256, 0, stream>>>(h1, w2b, b2, nullptr,
                                             h2, 1024, 4096, 0);
    // 7) out = LN(x1b + h2)  (fp32 out)
    ln_bf16_f32<<<8192, 256, 0, stream>>>(x1b, h2, ln2_g, ln2_b, out);
}